// Round 13
// baseline (1133.566 us; speedup 1.0000x reference)
//
#include <hip/hip_runtime.h>
#include <hip/hip_bf16.h>
#include <math.h>

#define BB 8
#define TT 1024
#define DD 512
#define FFD 2048
#define HH 8
#define HDD 64
#define KW 15
#define MR (BB*TT)   // 8192 rows
#define QKVN 1536
#define NBLK 512     // 2 blocks/CU via __launch_bounds__(256,2): co-resident

typedef __attribute__((ext_vector_type(8))) short short8;   // 8 bf16 = 4 VGPRs
typedef __attribute__((ext_vector_type(4))) short short4v;  // 8 bytes
typedef __attribute__((ext_vector_type(4))) float f32x4;
typedef __hip_bfloat16 bf16;

__device__ __forceinline__ float bf2f(unsigned u16) {
    return __uint_as_float(u16 << 16);
}

__device__ __forceinline__ void async_copy16(const void* g, void* l) {
    __builtin_amdgcn_global_load_lds(
        (const __attribute__((address_space(1))) void*)g,
        (__attribute__((address_space(3))) void*)l, 16, 0, 0);
}

__device__ __forceinline__ float gelu_exact(float v) {
    return 0.5f * v * (1.0f + erff(v * 0.70710678118654752f));
}

// ---------------------------------------------------------------------------
// Software grid barrier v2. Round-12 failure mode: polling with atomicAdd
// (RMW) serialized ~2500 req/µs against ~30/µs same-address RMW service at
// the owning L2 -> ~50 µs/barrier. Fix: poll with a device-scope ATOMIC LOAD
// (coherent read, no exclusive ownership, doesn't serialize like RMW) +
// s_sleep(32) backoff. Signal remains one release fetch_add per block
// (512 RMWs/barrier total — negligible).
// ---------------------------------------------------------------------------
__device__ __forceinline__ void grid_barrier(unsigned* cnt, int phase) {
    __syncthreads();
    if (threadIdx.x == 0) {
        __threadfence();   // release: prior writes visible device-wide
        __hip_atomic_fetch_add(cnt, 1u, __ATOMIC_RELEASE,
                               __HIP_MEMORY_SCOPE_AGENT);
        const unsigned target = (unsigned)phase * NBLK;
        while (__hip_atomic_load(cnt, __ATOMIC_ACQUIRE,
                                 __HIP_MEMORY_SCOPE_AGENT) < target)
            __builtin_amdgcn_s_sleep(32);
        __threadfence();   // acquire: discard stale cached lines
    }
    __syncthreads();
}

// ---------------------------------------------------------------------------
struct MegaArgs {
    // weight-transpose descriptors
    const float* wsrc[10];
    bf16*        wdst[10];
    int          wK[10];
    int          wlgNT[10];
    float        wscale[10];
    int          woff[10];
    // biases / params
    const float *bq, *bk, *bv;
    float*       bqkv;
    const float *x;
    const float *g1, *b1, *ga, *ba, *gc, *bc, *g2, *b2;
    const float *bff1, *bff2, *bo, *bcp, *bco, *bf1, *bf2;
    const float *dwk, *dwb, *bn_g, *bn_b, *bn_m, *bn_v;
    // transposed weights (ws)
    const bf16 *Wff1t, *Wff2t, *Wqkvt, *Wot, *Wcpt, *Wcot, *Wf1t, *Wf2t;
    // activations (ws)
    bf16 *lnb, *lnab, *qkvb, *Vtb, *ctxb, *xffb, *bigb, *c2b;
    float* out;
    unsigned* bar;
};

// ---------------------------------------------------------------------------
// Phase bodies — byte-identical math to the proven round-10 kernels.
// ---------------------------------------------------------------------------
__device__ __forceinline__ void dev_ln(int job, const float* x, const float* g,
                                       const float* b, bf16* out) {
    int wave = (job * 256 + (int)threadIdx.x) >> 6;
    int lane = threadIdx.x & 63;
    const float* row = x + (size_t)wave * DD;
    float4 v0 = ((const float4*)row)[lane];
    float4 v1 = ((const float4*)row)[64 + lane];
    float s  = v0.x + v0.y + v0.z + v0.w + v1.x + v1.y + v1.z + v1.w;
    float ss = v0.x*v0.x + v0.y*v0.y + v0.z*v0.z + v0.w*v0.w
             + v1.x*v1.x + v1.y*v1.y + v1.z*v1.z + v1.w*v1.w;
    #pragma unroll
    for (int off = 32; off >= 1; off >>= 1) {
        s  += __shfl_xor(s,  off, 64);
        ss += __shfl_xor(ss, off, 64);
    }
    float mean = s * (1.0f / DD);
    float var  = ss * (1.0f / DD) - mean * mean;
    float r    = rsqrtf(var + 1e-3f);
    float4 g0 = ((const float4*)g)[lane];
    float4 g1 = ((const float4*)g)[64 + lane];
    float4 b0 = ((const float4*)b)[lane];
    float4 b1 = ((const float4*)b)[64 + lane];
    alignas(8) bf16 o0[4], o1[4];
    o0[0] = __float2bfloat16((v0.x - mean) * r * g0.x + b0.x);
    o0[1] = __float2bfloat16((v0.y - mean) * r * g0.y + b0.y);
    o0[2] = __float2bfloat16((v0.z - mean) * r * g0.z + b0.z);
    o0[3] = __float2bfloat16((v0.w - mean) * r * g0.w + b0.w);
    o1[0] = __float2bfloat16((v1.x - mean) * r * g1.x + b1.x);
    o1[1] = __float2bfloat16((v1.y - mean) * r * g1.y + b1.y);
    o1[2] = __float2bfloat16((v1.z - mean) * r * g1.z + b1.z);
    o1[3] = __float2bfloat16((v1.w - mean) * r * g1.w + b1.w);
    bf16* orow = out + (size_t)wave * DD;
    *(short4v*)(orow + lane * 4)       = *(const short4v*)o0;
    *(short4v*)(orow + 256 + lane * 4) = *(const short4v*)o1;
}

__device__ __forceinline__ void dev_prep(int bid, const MegaArgs& A, bf16* smem) {
    if (bid == 1536) {   // bias concat
        #pragma unroll
        for (int it = 0; it < 6; ++it) {
            int i = it * 256 + threadIdx.x;
            float v = i < 512 ? A.bq[i] * 0.125f
                              : (i < 1024 ? A.bk[i - 512] : A.bv[i - 1024]);
            A.bqkv[i] = v;
        }
        return;
    }
    if (bid > 1536) {    // dual LN (shared stats), 4 rows/job
        int wave = ((bid - 1537) * 256 + (int)threadIdx.x) >> 6;
        int lane = threadIdx.x & 63;
        const float* row = A.x + (size_t)wave * DD;
        float4 v0 = ((const float4*)row)[lane];
        float4 v1 = ((const float4*)row)[64 + lane];
        float s  = v0.x + v0.y + v0.z + v0.w + v1.x + v1.y + v1.z + v1.w;
        float ss = v0.x*v0.x + v0.y*v0.y + v0.z*v0.z + v0.w*v0.w
                 + v1.x*v1.x + v1.y*v1.y + v1.z*v1.z + v1.w*v1.w;
        #pragma unroll
        for (int off = 32; off >= 1; off >>= 1) {
            s  += __shfl_xor(s,  off, 64);
            ss += __shfl_xor(ss, off, 64);
        }
        float mean = s * (1.0f / DD);
        float var  = ss * (1.0f / DD) - mean * mean;
        float r    = rsqrtf(var + 1e-3f);
        float n0x = (v0.x - mean) * r, n0y = (v0.y - mean) * r,
              n0z = (v0.z - mean) * r, n0w = (v0.w - mean) * r;
        float n1x = (v1.x - mean) * r, n1y = (v1.y - mean) * r,
              n1z = (v1.z - mean) * r, n1w = (v1.w - mean) * r;
        {
            float4 g0 = ((const float4*)A.g1)[lane];
            float4 gg = ((const float4*)A.g1)[64 + lane];
            float4 b0 = ((const float4*)A.b1)[lane];
            float4 bb = ((const float4*)A.b1)[64 + lane];
            alignas(8) bf16 o0[4], o1[4];
            o0[0] = __float2bfloat16(n0x * g0.x + b0.x);
            o0[1] = __float2bfloat16(n0y * g0.y + b0.y);
            o0[2] = __float2bfloat16(n0z * g0.z + b0.z);
            o0[3] = __float2bfloat16(n0w * g0.w + b0.w);
            o1[0] = __float2bfloat16(n1x * gg.x + bb.x);
            o1[1] = __float2bfloat16(n1y * gg.y + bb.y);
            o1[2] = __float2bfloat16(n1z * gg.z + bb.z);
            o1[3] = __float2bfloat16(n1w * gg.w + bb.w);
            bf16* orow = A.lnb + (size_t)wave * DD;
            *(short4v*)(orow + lane * 4)       = *(const short4v*)o0;
            *(short4v*)(orow + 256 + lane * 4) = *(const short4v*)o1;
        }
        {
            float4 g0 = ((const float4*)A.ga)[lane];
            float4 gg = ((const float4*)A.ga)[64 + lane];
            float4 b0 = ((const float4*)A.ba)[lane];
            float4 bb = ((const float4*)A.ba)[64 + lane];
            alignas(8) bf16 o0[4], o1[4];
            o0[0] = __float2bfloat16(n0x * g0.x + b0.x);
            o0[1] = __float2bfloat16(n0y * g0.y + b0.y);
            o0[2] = __float2bfloat16(n0z * g0.z + b0.z);
            o0[3] = __float2bfloat16(n0w * g0.w + b0.w);
            o1[0] = __float2bfloat16(n1x * gg.x + bb.x);
            o1[1] = __float2bfloat16(n1y * gg.y + bb.y);
            o1[2] = __float2bfloat16(n1z * gg.z + bb.z);
            o1[3] = __float2bfloat16(n1w * gg.w + bb.w);
            bf16* orow = A.lnab + (size_t)wave * DD;
            *(short4v*)(orow + lane * 4)       = *(const short4v*)o0;
            *(short4v*)(orow + 256 + lane * 4) = *(const short4v*)o1;
        }
        return;
    }
    // weight-transpose tile
    bf16 (*T)[72] = (bf16(*)[72])smem;
    int e = 0;
    #pragma unroll
    for (int i = 1; i < 10; ++i) e = (bid >= A.woff[i]) ? i : e;
    const float* W  = A.wsrc[e];
    bf16*        Wt = A.wdst[e];
    const int    K  = A.wK[e];
    const int    lg = A.wlgNT[e];
    const float  scale = A.wscale[e];
    const int local = bid - A.woff[e];
    const int bx = local & ((1 << lg) - 1);
    const int by = local >> lg;
    const int k0 = by * 64;
    const int n0 = bx * 64;
    const int N  = (1 << lg) * 64;
    const int tid = threadIdx.x;
    #pragma unroll
    for (int it = 0; it < 4; ++it) {
        int lin = it * 256 + tid;
        int kl  = lin >> 4;
        int nq  = (lin & 15) * 4;
        float4 v = *(const float4*)(W + (size_t)(k0 + kl) * N + n0 + nq);
        T[nq + 0][kl] = __float2bfloat16(v.x * scale);
        T[nq + 1][kl] = __float2bfloat16(v.y * scale);
        T[nq + 2][kl] = __float2bfloat16(v.z * scale);
        T[nq + 3][kl] = __float2bfloat16(v.w * scale);
    }
    __syncthreads();
    #pragma unroll
    for (int it = 0; it < 4; ++it) {
        int lin = it * 256 + tid;
        int nl  = lin >> 4;
        int kq  = (lin & 15) * 4;
        *(short4v*)(Wt + (size_t)(n0 + nl) * K + k0 + kq) = *(const short4v*)&T[nl][kq];
    }
    __syncthreads();   // T reused by next job
}

// Generic GEMM body (XCD-aware swizzle preserved: flat&7 == blockIdx&7).
template<int BN, int OP, int RESMODE, int OUTMODE>
__device__ __forceinline__ void dev_gemm(int flat, bf16* smem,
    const bf16* __restrict__ A, const bf16* __restrict__ Bt,
    const float* __restrict__ bias, const float* __restrict__ res1,
    const bf16* __restrict__ res2, float s2, void* __restrict__ Cout,
    int N, int Kd, int nxb)
{
    constexpr int NT = BN / 32;
    bf16 (*As)[64] = (bf16(*)[64])smem;            // 128 rows
    bf16 (*Bs)[64] = (bf16(*)[64])(smem + 128 * 64);
    const int tid  = threadIdx.x;
    const int w    = tid >> 6;
    const int lane = tid & 63;
    const int quad = lane >> 4;
    const int l16  = lane & 15;
    const int wm   = w >> 1, wn = w & 1;

    const int c8 = flat & 7;
    const int j  = flat >> 3;
    const int jy = j / nxb;
    const int m0 = (c8 * 8 + jy) * 128;
    const int n0 = (j - jy * nxb) * BN;

    const int srow = lane >> 3;
    const int scol = ((lane & 7) ^ srow) * 8;

    const bf16* Ap = A  + (size_t)(m0 + w * 32 + srow) * Kd + scol;
    const bf16* Bp = Bt + (size_t)(n0 + w * (BN / 4) + srow) * Kd + scol;

    f32x4 acc[4][NT] = {};

    for (int k0 = 0; k0 < Kd; k0 += 64) {
        #pragma unroll
        for (int i = 0; i < 4; ++i)
            async_copy16(Ap + (size_t)(i * 8) * Kd + k0, &As[w * 32 + i * 8][0]);
        #pragma unroll
        for (int i = 0; i < BN / 32; ++i)
            async_copy16(Bp + (size_t)(i * 8) * Kd + k0, &Bs[w * (BN / 4) + i * 8][0]);
        __syncthreads();
        #pragma unroll
        for (int ks = 0; ks < 2; ++ks) {
            short8 af[4], bfr[NT];
            #pragma unroll
            for (int mt = 0; mt < 4; ++mt) {
                const int row = wm * 64 + mt * 16 + l16;
                const int c   = ((ks * 4 + quad) ^ (row & 7)) * 16;
                af[mt] = *(const short8*)((const char*)&As[row][0] + c);
            }
            #pragma unroll
            for (int nt = 0; nt < NT; ++nt) {
                const int col = wn * (BN / 2) + nt * 16 + l16;
                const int c   = ((ks * 4 + quad) ^ (col & 7)) * 16;
                bfr[nt] = *(const short8*)((const char*)&Bs[col][0] + c);
            }
            #pragma unroll
            for (int mt = 0; mt < 4; ++mt)
                #pragma unroll
                for (int nt = 0; nt < NT; ++nt)
                    acc[mt][nt] = __builtin_amdgcn_mfma_f32_16x16x32_bf16(
                        af[mt], bfr[nt], acc[mt][nt], 0, 0, 0);
        }
        __syncthreads();
    }

    const int crow0 = m0 + wm * 64 + quad * 4;
    const int ccol0 = n0 + wn * (BN / 2) + l16;
    #pragma unroll
    for (int nt = 0; nt < NT; ++nt) {
        const int col = ccol0 + nt * 16;
        const float bv = bias[col];
        #pragma unroll
        for (int mt = 0; mt < 4; ++mt) {
            #pragma unroll
            for (int r = 0; r < 4; ++r) {
                const int row = crow0 + mt * 16 + r;
                const size_t off = (size_t)row * N + col;
                float o = acc[mt][nt][r] + bv;
                if (OP == 1)      o = fmaxf(o, 0.f);
                else if (OP == 2) o = gelu_exact(o);
                if (RESMODE >= 1) o += res1[off];
                if (RESMODE == 2) o += s2 * __bfloat162float(res2[off]);
                if (OUTMODE == 0) ((float*)Cout)[off] = o;
                else              ((bf16*)Cout)[off]  = __float2bfloat16(o);
            }
        }
    }
}

// FF1 + QKV fused body (K=512; QKV emits Q/K + transposed V).
__device__ __forceinline__ void dev_ffqkv(int job, bf16* smem, const MegaArgs& Ar) {
    bf16 (*As)[64] = (bf16(*)[64])smem;
    bf16 (*Bs)[64] = (bf16(*)[64])(smem + 128 * 64);
    const int tid  = threadIdx.x;
    const int w    = tid >> 6;
    const int lane = tid & 63;
    const int quad = lane >> 4;
    const int l16  = lane & 15;
    const int wm   = w >> 1, wn = w & 1;

    const bool jobq = job >= 1024;
    const int  flat = jobq ? job - 1024 : job;
    const int  nxb  = jobq ? 12 : 16;
    const int  N    = jobq ? QKVN : FFD;
    const bf16* A   = jobq ? Ar.lnab : Ar.lnb;
    const bf16* Bt  = jobq ? Ar.Wqkvt : Ar.Wff1t;
    const float* bias = jobq ? Ar.bqkv : Ar.bff1;

    const int c8 = flat & 7;
    const int j  = flat >> 3;
    const int jy = j / nxb;
    const int m0 = (c8 * 8 + jy) * 128;
    const int n0 = (j - jy * nxb) * 128;

    const int srow = lane >> 3;
    const int scol = ((lane & 7) ^ srow) * 8;

    const bf16* Ap = A  + (size_t)(m0 + w * 32 + srow) * DD + scol;
    const bf16* Bp = Bt + (size_t)(n0 + w * 32 + srow) * DD + scol;

    f32x4 acc[4][4] = {};

    for (int k0 = 0; k0 < DD; k0 += 64) {
        #pragma unroll
        for (int i = 0; i < 4; ++i) {
            async_copy16(Ap + (size_t)(i * 8) * DD + k0, &As[w * 32 + i * 8][0]);
            async_copy16(Bp + (size_t)(i * 8) * DD + k0, &Bs[w * 32 + i * 8][0]);
        }
        __syncthreads();
        #pragma unroll
        for (int ks = 0; ks < 2; ++ks) {
            short8 af[4], bfr[4];
            #pragma unroll
            for (int mt = 0; mt < 4; ++mt) {
                const int row = wm * 64 + mt * 16 + l16;
                const int c   = ((ks * 4 + quad) ^ (row & 7)) * 16;
                af[mt] = *(const short8*)((const char*)&As[row][0] + c);
            }
            #pragma unroll
            for (int nt = 0; nt < 4; ++nt) {
                const int col = wn * 64 + nt * 16 + l16;
                const int c   = ((ks * 4 + quad) ^ (col & 7)) * 16;
                bfr[nt] = *(const short8*)((const char*)&Bs[col][0] + c);
            }
            #pragma unroll
            for (int mt = 0; mt < 4; ++mt)
                #pragma unroll
                for (int nt = 0; nt < 4; ++nt)
                    acc[mt][nt] = __builtin_amdgcn_mfma_f32_16x16x32_bf16(
                        af[mt], bfr[nt], acc[mt][nt], 0, 0, 0);
        }
        __syncthreads();
    }

    const int crow0 = m0 + wm * 64 + quad * 4;
    const int ccol0 = n0 + wn * 64 + l16;
    #pragma unroll
    for (int nt = 0; nt < 4; ++nt) {
        const int col = ccol0 + nt * 16;
        const float bv = bias[col];
        #pragma unroll
        for (int mt = 0; mt < 4; ++mt) {
            if (jobq) {
                alignas(8) bf16 o4[4];
                #pragma unroll
                for (int r = 0; r < 4; ++r)
                    o4[r] = __float2bfloat16(acc[mt][nt][r] + bv);
                if (col < 1024) {
                    #pragma unroll
                    for (int r = 0; r < 4; ++r)
                        Ar.qkvb[(size_t)(crow0 + mt * 16 + r) * QKVN + col] = o4[r];
                } else {
                    const int dg   = col - 1024;
                    const int rowt = crow0 + mt * 16;
                    const int bb   = rowt >> 10, t0 = rowt & 1023;
                    const int bh2  = bb * 8 + (dg >> 6), d = dg & 63;
                    *(short4v*)(Ar.Vtb + ((size_t)bh2 * 64 + d) * TT + t0) =
                        *(const short4v*)o4;
                }
            } else {
                #pragma unroll
                for (int r = 0; r < 4; ++r) {
                    const float o = fmaxf(acc[mt][nt][r] + bv, 0.f);
                    Ar.bigb[(size_t)(crow0 + mt * 16 + r) * FFD + col] =
                        __float2bfloat16(o);
                }
            }
        }
    }
}

// fattn v4 + FF2 fused body.
__device__ __forceinline__ void dev_ff2attn(int job, bf16* smem, const MegaArgs& Ar) {
    const int tid  = threadIdx.x;
    const int w    = tid >> 6;
    const int lane = tid & 63;
    const int quad = lane >> 4;
    const int l16  = lane & 15;

    if (job < 512) {
        // ---------------- flash attention v4 ----------------
        typedef bf16 (*tile_t)[64][64];
        tile_t Ks = (tile_t)smem;
        tile_t Vs = (tile_t)(smem + 2 * 64 * 64);
        const int bh = job & 63;
        const int bi = 7 - (job >> 6);
        const int b = bh >> 3, h = bh & 7;

        const bf16* Qg = Ar.qkvb + (size_t)(b * TT) * QKVN + h * 64;
        const bf16* Kg = Ar.qkvb + (size_t)(b * TT) * QKVN + 512 + h * 64;
        const bf16* Vg = Ar.Vtb  + (size_t)bh * 64 * TT;

        const int qL = bi * 128 + w * 16;
        const int qH = qL + 64;
        short8 qfL0 = *(const short8*)(Qg + (size_t)(qL + l16) * QKVN + quad * 8);
        short8 qfL1 = *(const short8*)(Qg + (size_t)(qL + l16) * QKVN + 32 + quad * 8);
        short8 qfH0 = *(const short8*)(Qg + (size_t)(qH + l16) * QKVN + quad * 8);
        short8 qfH1 = *(const short8*)(Qg + (size_t)(qH + l16) * QKVN + 32 + quad * 8);

        const int sgrow  = lane >> 3;
        const int sgchnk = lane & 7;

        f32x4 caccL[4] = {}, caccH[4] = {};
        float lL = 0.f, lH = 0.f;
        const int prow_base = ((l16 >> 2) << 3) + (l16 & 3);
        const int smax = 2 * bi + 1;

        #pragma unroll
        for (int i = 0; i < 2; ++i) {
            const int rowbase = w * 8 + i * 32;
            const int row = rowbase + sgrow;
            const int fR = (row & 3) | (((row >> 3) & 1) << 2);
            const int sc = sgchnk ^ fR;
            async_copy16(Kg + (size_t)row * QKVN + sc * 8, &Ks[0][rowbase][0]);
            async_copy16(Vg + (size_t)row * TT + sc * 8,   &Vs[0][rowbase][0]);
        }

        int buf = 0;
        for (int s = 0; s <= smax; ++s) {
            __syncthreads();
            if (s < smax) {
                const int kn = (s + 1) * 64;
                #pragma unroll
                for (int i = 0; i < 2; ++i) {
                    const int rowbase = w * 8 + i * 32;
                    const int row = rowbase + sgrow;
                    const int fR = (row & 3) | (((row >> 3) & 1) << 2);
                    const int sc = sgchnk ^ fR;
                    async_copy16(Kg + (size_t)(kn + row) * QKVN + sc * 8,
                                 &Ks[buf ^ 1][rowbase][0]);
                    async_copy16(Vg + (size_t)row * TT + kn + sc * 8,
                                 &Vs[buf ^ 1][rowbase][0]);
                }
            }
            const int k0 = s * 64;
            const bool doL = (s < smax);

            f32x4 sTL[4], sTH[4];
            #pragma unroll
            for (int s4 = 0; s4 < 4; ++s4) {
                const int prow = prow_base + (s4 >> 1) * 32 + (s4 & 1) * 4;
                const int fR = (prow & 3) | (((prow >> 3) & 1) << 2);
                short8 ka = *(const short8*)&Ks[buf][prow][(quad ^ fR) * 8];
                short8 kb = *(const short8*)&Ks[buf][prow][((4 + quad) ^ fR) * 8];
                f32x4 zH = {0.f, 0.f, 0.f, 0.f};
                zH = __builtin_amdgcn_mfma_f32_16x16x32_bf16(ka, qfH0, zH, 0, 0, 0);
                sTH[s4] = __builtin_amdgcn_mfma_f32_16x16x32_bf16(kb, qfH1, zH, 0, 0, 0);
                if (doL) {
                    f32x4 zL = {0.f, 0.f, 0.f, 0.f};
                    zL = __builtin_amdgcn_mfma_f32_16x16x32_bf16(ka, qfL0, zL, 0, 0, 0);
                    sTL[s4] = __builtin_amdgcn_mfma_f32_16x16x32_bf16(kb, qfL1, zL, 0, 0, 0);
                }
            }

            alignas(16) bf16 pbH[16], pbL[16];
            if (s == smax) {
                const int qg = qH + l16;
                #pragma unroll
                for (int s4 = 0; s4 < 4; ++s4)
                    #pragma unroll
                    for (int r = 0; r < 4; ++r) {
                        const int key = k0 + (s4 >> 1) * 32 + quad * 8 + (s4 & 1) * 4 + r;
                        const float p = (key <= qg) ? __expf(sTH[s4][r]) : 0.f;
                        lH += p;
                        pbH[s4 * 4 + r] = __float2bfloat16(p);
                    }
            } else {
                #pragma unroll
                for (int s4 = 0; s4 < 4; ++s4)
                    #pragma unroll
                    for (int r = 0; r < 4; ++r) {
                        const float p = __expf(sTH[s4][r]);
                        lH += p;
                        pbH[s4 * 4 + r] = __float2bfloat16(p);
                    }
            }
            if (doL) {
                if (s == smax - 1) {
                    const int qg = qL + l16;
                    #pragma unroll
                    for (int s4 = 0; s4 < 4; ++s4)
                        #pragma unroll
                        for (int r = 0; r < 4; ++r) {
                            const int key = k0 + (s4 >> 1) * 32 + quad * 8 + (s4 & 1) * 4 + r;
                            const float p = (key <= qg) ? __expf(sTL[s4][r]) : 0.f;
                            lL += p;
                            pbL[s4 * 4 + r] = __float2bfloat16(p);
                        }
                } else {
                    #pragma unroll
                    for (int s4 = 0; s4 < 4; ++s4)
                        #pragma unroll
                        for (int r = 0; r < 4; ++r) {
                            const float p = __expf(sTL[s4][r]);
                            lL += p;
                            pbL[s4 * 4 + r] = __float2bfloat16(p);
                        }
                }
            }
            const short8 pfH0 = *(const short8*)&pbH[0];
            const short8 pfH1 = *(const short8*)&pbH[8];
            const short8 pfL0 = *(const short8*)&pbL[0];
            const short8 pfL1 = *(const short8*)&pbL[8];

            #pragma unroll
            for (int g = 0; g < 4; ++g) {
                const int vrow = g * 16 + l16;
                const int fR = (vrow & 3) | (((vrow >> 3) & 1) << 2);
                short8 va = *(const short8*)&Vs[buf][vrow][(quad ^ fR) * 8];
                short8 vb = *(const short8*)&Vs[buf][vrow][((4 + quad) ^ fR) * 8];
                caccH[g] = __builtin_amdgcn_mfma_f32_16x16x32_bf16(va, pfH0, caccH[g], 0, 0, 0);
                caccH[g] = __builtin_amdgcn_mfma_f32_16x16x32_bf16(vb, pfH1, caccH[g], 0, 0, 0);
                if (doL) {
                    caccL[g] = __builtin_amdgcn_mfma_f32_16x16x32_bf16(va, pfL0, caccL[g], 0, 0, 0);
                    caccL[g] = __builtin_amdgcn_mfma_f32_16x16x32_bf16(vb, pfL1, caccL[g], 0, 0, 0);
                }
            }
            buf ^= 1;
        }

        lL += __shfl_xor(lL, 16, 64);
        lL += __shfl_xor(lL, 32, 64);
        lH += __shfl_xor(lH, 16, 64);
        lH += __shfl_xor(lH, 32, 64);
        const float invL = 1.0f / lL;
        const float invH = 1.0f / lH;

        bf16* CbL = Ar.ctxb + (size_t)(b * TT + qL + l16) * DD + h * 64;
        bf16* CbH = Ar.ctxb + (size_t)(b * TT + qH + l16) * DD + h * 64;
        #pragma unroll
        for (int g = 0; g < 4; ++g) {
            alignas(8) bf16 oL[4], oH[4];
            #pragma unroll
            for (int r = 0; r < 4; ++r) {
                oL[r] = __float2bfloat16(caccL[g][r] * invL);
                oH[r] = __float2bfloat16(caccH[g][r] * invH);
            }
            *(short4v*)(CbL + g * 16 + quad * 4) = *(const short4v*)oL;
            *(short4v*)(CbH + g * 16 + quad * 4) = *(const short4v*)oH;
        }
        __syncthreads();   // Ks/Vs reused by next job
    } else {
        // ---------------- FF2: xff = bigb @ Wff2t + bff2 ----------------
        bf16 (*As)[64] = (bf16(*)[64])smem;
        bf16 (*Bs)[64] = (bf16(*)[64])(smem + 128 * 64);
        const int wm = w >> 1, wn = w & 1;

        const int flat = job - 512;
        const int c8 = flat & 7;
        const int j  = flat >> 3;
        const int jy = j >> 3;          // nxb = 8
        const int m0 = (c8 * 8 + jy) * 128;
        const int n0 = (j & 7) * 64;

        const int srow = lane >> 3;
        const int scol = ((lane & 7) ^ srow) * 8;

        const bf16* Ap = Ar.bigb  + (size_t)(m0 + w * 32 + srow) * FFD + scol;
        const bf16* Bp = Ar.Wff2t + (size_t)(n0 + w * 16 + srow) * FFD + scol;

        f32x4 acc[4][2] = {};

        for (int k0 = 0; k0 < FFD; k0 += 64) {
            #pragma unroll
            for (int i = 0; i < 4; ++i)
                async_copy16(Ap + (size_t)(i * 8) * FFD + k0, &As[w * 32 + i * 8][0]);
            #pragma unroll
            for (int i = 0; i < 2; ++i)
                async_copy16(Bp + (size_t)(i * 8) * FFD + k0, &Bs[w * 16 + i * 8][0]);
            __syncthreads();
            #pragma unroll
            for (int ks = 0; ks < 2; ++ks) {
                short8 af[4], bfr[2];
                #pragma unroll
                for (int mt = 0; mt < 4; ++mt) {
                    const int row = wm * 64 + mt * 16 + l16;
                    const int c   = ((ks * 4 + quad) ^ (row & 7)) * 16;
                    af[mt] = *(const short8*)((const char*)&As[row][0] + c);
                }
                #pragma unroll
                for (int nt = 0; nt < 2; ++nt) {
                    const int col = wn * 32 + nt * 16 + l16;
                    const int c   = ((ks * 4 + quad) ^ (col & 7)) * 16;
                    bfr[nt] = *(const short8*)((const char*)&Bs[col][0] + c);
                }
                #pragma unroll
                for (int mt = 0; mt < 4; ++mt)
                    #pragma unroll
                    for (int nt = 0; nt < 2; ++nt)
                        acc[mt][nt] = __builtin_amdgcn_mfma_f32_16x16x32_bf16(
                            af[mt], bfr[nt], acc[mt][nt], 0, 0, 0);
            }
            __syncthreads();
        }

        const int crow0 = m0 + wm * 64 + quad * 4;
        const int ccol0 = n0 + wn * 32 + l16;
        #pragma unroll
        for (int nt = 0; nt < 2; ++nt) {
            const int col = ccol0 + nt * 16;
            const float bv = Ar.bff2[col];
            #pragma unroll
            for (int mt = 0; mt < 4; ++mt)
                #pragma unroll
                for (int r = 0; r < 4; ++r) {
                    const int row = crow0 + mt * 16 + r;
                    Ar.xffb[(size_t)row * DD + col] =
                        __float2bfloat16(acc[mt][nt][r] + bv);
                }
        }
    }
}

__device__ __forceinline__ void dev_dwconv(int job, const MegaArgs& A) {
    const int C2 = 2 * DD;
    const int lin = job * 256 + threadIdx.x;
    const int chp = lin & 511;
    const int ch  = chp << 1;
    const int tch = lin >> 9;
    const int row0 = tch << 3;
    const int t0   = row0 & (TT - 1);
    const bf16* c1 = A.bigb;

    float w0[KW], w1[KW];
    #pragma unroll
    for (int i = 0; i < KW; ++i) {
        w0[i] = A.dwk[i * C2 + ch];
        w1[i] = A.dwk[i * C2 + ch + 1];
    }
    const float a0 = rsqrtf(A.bn_v[ch] + 1e-3f) * A.bn_g[ch];
    const float a1 = rsqrtf(A.bn_v[ch + 1] + 1e-3f) * A.bn_g[ch + 1];
    const float c0 = (A.dwb[ch] - A.bn_m[ch]) * a0 + A.bn_b[ch];
    const float c1v = (A.dwb[ch + 1] - A.bn_m[ch + 1]) * a1 + A.bn_b[ch + 1];

    float x0[22], x1[22];
    if (t0 >= KW - 1) {
        #pragma unroll
        for (int i = 0; i < 22; ++i) {
            unsigned u = *(const unsigned*)(c1 + (size_t)(row0 - (KW - 1) + i) * C2 + ch);
            x0[i] = bf2f(u & 0xffff);
            x1[i] = bf2f(u >> 16);
        }
    } else {
        #pragma unroll
        for (int i = 0; i < 22; ++i) {
            unsigned u = 0;
            if (t0 - (KW - 1) + i >= 0)
                u = *(const unsigned*)(c1 + (size_t)(row0 - (KW - 1) + i) * C2 + ch);
            x0[i] = bf2f(u & 0xffff);
            x1[i] = bf2f(u >> 16);
        }
    }

    #pragma unroll
    for (int jj = 0; jj < 8; ++jj) {
        float s0 = 0.f, s1 = 0.f;
        #pragma unroll
        for (int i = 0; i < KW; ++i) {
            s0 += x0[jj + i] * w0[i];
            s1 += x1[jj + i] * w1[i];
        }
        s0 = s0 * a0 + c0;
        s1 = s1 * a1 + c1v;
        s0 = s0 / (1.f + __expf(-s0));
        s1 = s1 / (1.f + __expf(-s1));
        alignas(4) bf16 ob[2] = {__float2bfloat16(s0), __float2bfloat16(s1)};
        *(unsigned*)(A.c2b + (size_t)(row0 + jj) * C2 + ch) = *(const unsigned*)ob;
    }
}

// ---------------------------------------------------------------------------
// The mega-kernel: 11 phases separated by software grid barriers (v2).
// 512 blocks, 2/CU enforced by __launch_bounds__(256,2) -> all co-resident.
// ---------------------------------------------------------------------------
__global__ __launch_bounds__(256, 2) void mega_kernel(MegaArgs A) {
    __shared__ alignas(16) bf16 smem[16384];   // 32 KB union
    const int blk = blockIdx.x;

    // P1: prep (wtrans 1536 + bias 1 + dual-LN 2048)
    for (int job = blk; job < 3585; job += NBLK) dev_prep(job, A, smem);
    grid_barrier(A.bar, 1);
    // P2: FF1 + QKV
    for (int job = blk; job < 1792; job += NBLK) dev_ffqkv(job, smem, A);
    grid_barrier(A.bar, 2);
    // P3: fattn + FF2
    for (int job = blk; job < 1024; job += NBLK) dev_ff2attn(job, smem, A);
    grid_barrier(A.bar, 3);
    // P4: x1 = x + 0.5*xff + ctx@Wo + bo -> out (fp32)
    dev_gemm<64, 0, 2, 0>(blk, smem, A.ctxb, A.Wot, A.bo, A.x, A.xffb, 0.5f,
                          A.out, DD, DD, 8);
    grid_barrier(A.bar, 4);
    // P5: lnc = LN(x1)
    for (int job = blk; job < 2048; job += NBLK) dev_ln(job, A.out, A.gc, A.bc, A.lnb);
    grid_barrier(A.bar, 5);
    // P6: c1 = gelu(lnc@Wcp + bcp)
    dev_gemm<128, 2, 0, 1>(blk, smem, A.lnb, A.Wcpt, A.bcp, nullptr, nullptr, 0.f,
                           A.bigb, 1024, DD, 8);
    grid_barrier(A.bar, 6);
    // P7: dwconv + BN + swish
    for (int job = blk; job < 2048; job += NBLK) dev_dwconv(job, A);
    grid_barrier(A.bar, 7);
    // P8: x2 = x1 + c2@Wco + bco (in-place on out)
    dev_gemm<64, 0, 1, 0>(blk, smem, A.c2b, A.Wcot, A.bco, A.out, nullptr, 0.f,
                          A.out, DD, 1024, 8);
    grid_barrier(A.bar, 8);
    // P9: ln2 = LN(x2)
    for (int job = blk; job < 2048; job += NBLK) dev_ln(job, A.out, A.g2, A.b2, A.lnb);
    grid_barrier(A.bar, 9);
    // P10: h2 = relu(ln2@Wf1 + bf1)
    for (int job = blk; job < 1024; job += NBLK)
        dev_gemm<128, 1, 0, 1>(job, smem, A.lnb, A.Wf1t, A.bf1, nullptr, nullptr, 0.f,
                               A.bigb, FFD, DD, 16);
    grid_barrier(A.bar, 10);
    // P11: out = x2 + h2@Wf2 + bf2
    dev_gemm<64, 0, 1, 0>(blk, smem, A.bigb, A.Wf2t, A.bf2, A.out, nullptr, 0.f,
                          A.out, DD, FFD, 8);
}

// ---------------------------------------------------------------------------
extern "C" void kernel_launch(void* const* d_in, const int* in_sizes, int n_in,
                              void* d_out, int out_size, void* d_ws, size_t ws_size,
                              hipStream_t stream) {
    const float* x    = (const float*)d_in[0];
    const float* g1   = (const float*)d_in[1];
    const float* b1   = (const float*)d_in[2];
    const float* Wff1 = (const float*)d_in[3];
    const float* bff1 = (const float*)d_in[4];
    const float* Wff2 = (const float*)d_in[5];
    const float* bff2 = (const float*)d_in[6];
    const float* ga   = (const float*)d_in[7];
    const float* ba   = (const float*)d_in[8];
    const float* Wq   = (const float*)d_in[9];
    const float* bq   = (const float*)d_in[10];
    const float* Wk   = (const float*)d_in[11];
    const float* bk   = (const float*)d_in[12];
    const float* Wv   = (const float*)d_in[13];
    const float* bv   = (const float*)d_in[14];
    const float* Wo   = (const float*)d_in[15];
    const float* bo   = (const float*)d_in[16];
    const float* gc   = (const float*)d_in[17];
    const float* bc   = (const float*)d_in[18];
    const float* Wcp  = (const float*)d_in[19];
    const float* bcp  = (const float*)d_in[20];
    const float* dwk  = (const float*)d_in[21];
    const float* dwb  = (const float*)d_in[22];
    const float* bn_g = (const float*)d_in[23];
    const float* bn_b = (const float*)d_in[24];
    const float* bn_m = (const float*)d_in[25];
    const float* bn_v = (const float*)d_in[26];
    const float* Wco  = (const float*)d_in[27];
    const float* bco  = (const float*)d_in[28];
    const float* g2   = (const float*)d_in[29];
    const float* b2   = (const float*)d_in[30];
    const float* Wf1  = (const float*)d_in[31];
    const float* bf1  = (const float*)d_in[32];
    const float* Wf2  = (const float*)d_in[33];
    const float* bf2  = (const float*)d_in[34];

    // ---- workspace layout ----
    char* p = (char*)d_ws;
    bf16* lnb   = (bf16*)p;  p += (size_t)MR * DD * 2;
    bf16* lnab  = (bf16*)p;  p += (size_t)MR * DD * 2;
    bf16* qkvb  = (bf16*)p;  p += (size_t)MR * QKVN * 2;
    bf16* Vtb   = (bf16*)p;  p += (size_t)MR * DD * 2;
    bf16* ctxb  = (bf16*)p;  p += (size_t)MR * DD * 2;
    bf16* xffb  = (bf16*)p;  p += (size_t)MR * DD * 2;
    bf16* bigb  = (bf16*)p;  p += (size_t)MR * FFD * 2;
    bf16* c2b   = (bf16*)p;  p += (size_t)MR * 1024 * 2;
    bf16* Wff1t = (bf16*)p;  p += (size_t)FFD * DD * 2;
    bf16* Wff2t = (bf16*)p;  p += (size_t)DD * FFD * 2;
    bf16* Wqkvt = (bf16*)p;  p += (size_t)QKVN * DD * 2;
    bf16* Wot   = (bf16*)p;  p += (size_t)DD * DD * 2;
    bf16* Wcpt  = (bf16*)p;  p += (size_t)1024 * DD * 2;
    bf16* Wcot  = (bf16*)p;  p += (size_t)DD * 1024 * 2;
    bf16* Wf1t  = (bf16*)p;  p += (size_t)FFD * DD * 2;
    bf16* Wf2t  = (bf16*)p;  p += (size_t)DD * FFD * 2;
    float* bqkv = (float*)p; p += QKVN * 4;
    unsigned* bar = (unsigned*)p; p += 256;   // barrier counter (zeroed below)

    MegaArgs A;
    auto set = [&](int i, const float* s, bf16* d, int K, int N, float sc, int off) {
        A.wsrc[i] = s; A.wdst[i] = d; A.wK[i] = K; A.wscale[i] = sc; A.woff[i] = off;
        int nt = N / 64, lg = 0; while ((1 << lg) < nt) ++lg; A.wlgNT[i] = lg;
    };
    set(0, Wff1, Wff1t, DD,  FFD, 1.f,    0);
    set(1, Wff2, Wff2t, FFD, DD,  1.f,    256);
    set(2, Wq,   Wqkvt,                DD, DD, 0.125f, 512);
    set(3, Wk,   Wqkvt + (size_t)512 * DD,  DD, DD, 1.f, 576);
    set(4, Wv,   Wqkvt + (size_t)1024 * DD, DD, DD, 1.f, 640);
    set(5, Wo,   Wot,   DD,  DD,  1.f,    704);
    set(6, Wcp,  Wcpt,  DD,  1024, 1.f,   768);
    set(7, Wco,  Wcot,  1024, DD, 1.f,    896);
    set(8, Wf1,  Wf1t,  DD,  FFD, 1.f,    1024);
    set(9, Wf2,  Wf2t,  FFD, DD,  1.f,    1280);
    A.bq = bq; A.bk = bk; A.bv = bv; A.bqkv = bqkv;
    A.x = x;
    A.g1 = g1; A.b1 = b1; A.ga = ga; A.ba = ba;
    A.gc = gc; A.bc = bc; A.g2 = g2; A.b2 = b2;
    A.bff1 = bff1; A.bff2 = bff2; A.bo = bo; A.bcp = bcp; A.bco = bco;
    A.bf1 = bf1; A.bf2 = bf2;
    A.dwk = dwk; A.dwb = dwb; A.bn_g = bn_g; A.bn_b = bn_b;
    A.bn_m = bn_m; A.bn_v = bn_v;
    A.Wff1t = Wff1t; A.Wff2t = Wff2t; A.Wqkvt = Wqkvt; A.Wot = Wot;
    A.Wcpt = Wcpt; A.Wcot = Wcot; A.Wf1t = Wf1t; A.Wf2t = Wf2t;
    A.lnb = lnb; A.lnab = lnab; A.qkvb = qkvb; A.Vtb = Vtb; A.ctxb = ctxb;
    A.xffb = xffb; A.bigb = bigb; A.c2b = c2b;
    A.out = (float*)d_out;
    A.bar = bar;

    hipMemsetAsync(bar, 0, 256, stream);
    mega_kernel<<<dim3(NBLK), dim3(256), 0, stream>>>(A);
}

// Round 14
// 382.923 us; speedup vs baseline: 2.9603x; 2.9603x over previous
//
#include <hip/hip_runtime.h>
#include <hip/hip_bf16.h>
#include <math.h>

#define BB 8
#define TT 1024
#define DD 512
#define FFD 2048
#define HH 8
#define HDD 64
#define KW 15
#define MR (BB*TT)   // 8192 rows
#define QKVN 1536

typedef __attribute__((ext_vector_type(8))) short short8;   // 8 bf16 = 4 VGPRs
typedef __attribute__((ext_vector_type(4))) short short4v;  // 8 bytes
typedef __attribute__((ext_vector_type(4))) float f32x4;
typedef __hip_bfloat16 bf16;

__device__ __forceinline__ float bf2f(unsigned u16) {
    return __uint_as_float(u16 << 16);
}

__device__ __forceinline__ void async_copy16(const void* g, void* l) {
    __builtin_amdgcn_global_load_lds(
        (const __attribute__((address_space(1))) void*)g,
        (__attribute__((address_space(3))) void*)l, 16, 0, 0);
}

__device__ __forceinline__ float gelu_exact(float v) {
    return 0.5f * v * (1.0f + erff(v * 0.70710678118654752f));
}

// ---------------------------------------------------------------------------
// Prep super-kernel: blocks 0..1535 weight transpose, 1536 bias concat,
// 1537..3584 dual LayerNorm (LN1+LNa share row stats). All independent.
// ---------------------------------------------------------------------------
struct PrepPack {
    const float* src[10];
    bf16*        dst[10];
    int          K[10];
    int          lgNT[10];
    float        scale[10];
    int          off[10];
    const float* bq; const float* bk; const float* bv;
    float*       bdst;
    const float* x;
    const float* g1; const float* b1; const float* ga; const float* ba;
    bf16* o1; bf16* o2;
};

__global__ __launch_bounds__(256) void prep_kernel(PrepPack P) {
    __shared__ alignas(16) bf16 T[64][72];
    const int bid = blockIdx.x;
    if (bid == 1536) {   // bias concat
        #pragma unroll
        for (int it = 0; it < 6; ++it) {
            int i = it * 256 + threadIdx.x;
            float v = i < 512 ? P.bq[i] * 0.125f
                              : (i < 1024 ? P.bk[i - 512] : P.bv[i - 1024]);
            P.bdst[i] = v;
        }
        return;
    }
    if (bid > 1536) {    // dual LN: 4 rows per block (wave per row)
        int wave = ((bid - 1537) * 256 + (int)threadIdx.x) >> 6;
        int lane = threadIdx.x & 63;
        const float* row = P.x + (size_t)wave * DD;
        float4 v0 = ((const float4*)row)[lane];
        float4 v1 = ((const float4*)row)[64 + lane];
        float s  = v0.x + v0.y + v0.z + v0.w + v1.x + v1.y + v1.z + v1.w;
        float ss = v0.x*v0.x + v0.y*v0.y + v0.z*v0.z + v0.w*v0.w
                 + v1.x*v1.x + v1.y*v1.y + v1.z*v1.z + v1.w*v1.w;
        #pragma unroll
        for (int off = 32; off >= 1; off >>= 1) {
            s  += __shfl_xor(s,  off, 64);
            ss += __shfl_xor(ss, off, 64);
        }
        float mean = s * (1.0f / DD);
        float var  = ss * (1.0f / DD) - mean * mean;
        float r    = rsqrtf(var + 1e-3f);
        float n0x = (v0.x - mean) * r, n0y = (v0.y - mean) * r,
              n0z = (v0.z - mean) * r, n0w = (v0.w - mean) * r;
        float n1x = (v1.x - mean) * r, n1y = (v1.y - mean) * r,
              n1z = (v1.z - mean) * r, n1w = (v1.w - mean) * r;
        {
            float4 g0 = ((const float4*)P.g1)[lane];
            float4 gg = ((const float4*)P.g1)[64 + lane];
            float4 b0 = ((const float4*)P.b1)[lane];
            float4 bb = ((const float4*)P.b1)[64 + lane];
            alignas(8) bf16 o0[4], o1[4];
            o0[0] = __float2bfloat16(n0x * g0.x + b0.x);
            o0[1] = __float2bfloat16(n0y * g0.y + b0.y);
            o0[2] = __float2bfloat16(n0z * g0.z + b0.z);
            o0[3] = __float2bfloat16(n0w * g0.w + b0.w);
            o1[0] = __float2bfloat16(n1x * gg.x + bb.x);
            o1[1] = __float2bfloat16(n1y * gg.y + bb.y);
            o1[2] = __float2bfloat16(n1z * gg.z + bb.z);
            o1[3] = __float2bfloat16(n1w * gg.w + bb.w);
            bf16* orow = P.o1 + (size_t)wave * DD;
            *(short4v*)(orow + lane * 4)       = *(const short4v*)o0;
            *(short4v*)(orow + 256 + lane * 4) = *(const short4v*)o1;
        }
        {
            float4 g0 = ((const float4*)P.ga)[lane];
            float4 gg = ((const float4*)P.ga)[64 + lane];
            float4 b0 = ((const float4*)P.ba)[lane];
            float4 bb = ((const float4*)P.ba)[64 + lane];
            alignas(8) bf16 o0[4], o1[4];
            o0[0] = __float2bfloat16(n0x * g0.x + b0.x);
            o0[1] = __float2bfloat16(n0y * g0.y + b0.y);
            o0[2] = __float2bfloat16(n0z * g0.z + b0.z);
            o0[3] = __float2bfloat16(n0w * g0.w + b0.w);
            o1[0] = __float2bfloat16(n1x * gg.x + bb.x);
            o1[1] = __float2bfloat16(n1y * gg.y + bb.y);
            o1[2] = __float2bfloat16(n1z * gg.z + bb.z);
            o1[3] = __float2bfloat16(n1w * gg.w + bb.w);
            bf16* orow = P.o2 + (size_t)wave * DD;
            *(short4v*)(orow + lane * 4)       = *(const short4v*)o0;
            *(short4v*)(orow + 256 + lane * 4) = *(const short4v*)o1;
        }
        return;
    }
    // weight transpose tile
    int e = 0;
    #pragma unroll
    for (int i = 1; i < 10; ++i) e = (bid >= P.off[i]) ? i : e;
    const float* W  = P.src[e];
    bf16*        Wt = P.dst[e];
    const int    K  = P.K[e];
    const int    lg = P.lgNT[e];
    const float  scale = P.scale[e];
    const int local = bid - P.off[e];
    const int bx = local & ((1 << lg) - 1);
    const int by = local >> lg;
    const int k0 = by * 64;
    const int n0 = bx * 64;
    const int N  = (1 << lg) * 64;
    const int tid = threadIdx.x;
    #pragma unroll
    for (int it = 0; it < 4; ++it) {
        int lin = it * 256 + tid;
        int kl  = lin >> 4;
        int nq  = (lin & 15) * 4;
        float4 v = *(const float4*)(W + (size_t)(k0 + kl) * N + n0 + nq);
        T[nq + 0][kl] = __float2bfloat16(v.x * scale);
        T[nq + 1][kl] = __float2bfloat16(v.y * scale);
        T[nq + 2][kl] = __float2bfloat16(v.z * scale);
        T[nq + 3][kl] = __float2bfloat16(v.w * scale);
    }
    __syncthreads();
    #pragma unroll
    for (int it = 0; it < 4; ++it) {
        int lin = it * 256 + tid;
        int nl  = lin >> 4;
        int kq  = (lin & 15) * 4;
        *(short4v*)(Wt + (size_t)(n0 + nl) * K + k0 + kq) = *(const short4v*)&T[nl][kq];
    }
}

// ---------------------------------------------------------------------------
// Single LayerNorm (steps 5, 9).
// ---------------------------------------------------------------------------
__global__ __launch_bounds__(256) void ln_kernel(const float* __restrict__ x,
                                                 const float* __restrict__ g,
                                                 const float* __restrict__ b,
                                                 bf16* __restrict__ out) {
    int wave = (blockIdx.x * blockDim.x + threadIdx.x) >> 6;
    int lane = threadIdx.x & 63;
    if (wave >= MR) return;
    const float* row = x + (size_t)wave * DD;
    float4 v0 = ((const float4*)row)[lane];
    float4 v1 = ((const float4*)row)[64 + lane];
    float s  = v0.x + v0.y + v0.z + v0.w + v1.x + v1.y + v1.z + v1.w;
    float ss = v0.x*v0.x + v0.y*v0.y + v0.z*v0.z + v0.w*v0.w
             + v1.x*v1.x + v1.y*v1.y + v1.z*v1.z + v1.w*v1.w;
    #pragma unroll
    for (int off = 32; off >= 1; off >>= 1) {
        s  += __shfl_xor(s,  off, 64);
        ss += __shfl_xor(ss, off, 64);
    }
    float mean = s * (1.0f / DD);
    float var  = ss * (1.0f / DD) - mean * mean;
    float r    = rsqrtf(var + 1e-3f);
    float4 g0 = ((const float4*)g)[lane];
    float4 g1 = ((const float4*)g)[64 + lane];
    float4 b0 = ((const float4*)b)[lane];
    float4 b1 = ((const float4*)b)[64 + lane];
    alignas(8) bf16 o0[4], o1[4];
    o0[0] = __float2bfloat16((v0.x - mean) * r * g0.x + b0.x);
    o0[1] = __float2bfloat16((v0.y - mean) * r * g0.y + b0.y);
    o0[2] = __float2bfloat16((v0.z - mean) * r * g0.z + b0.z);
    o0[3] = __float2bfloat16((v0.w - mean) * r * g0.w + b0.w);
    o1[0] = __float2bfloat16((v1.x - mean) * r * g1.x + b1.x);
    o1[1] = __float2bfloat16((v1.y - mean) * r * g1.y + b1.y);
    o1[2] = __float2bfloat16((v1.z - mean) * r * g1.z + b1.z);
    o1[3] = __float2bfloat16((v1.w - mean) * r * g1.w + b1.w);
    bf16* orow = out + (size_t)wave * DD;
    *(short4v*)(orow + lane * 4)       = *(const short4v*)o0;
    *(short4v*)(orow + 256 + lane * 4) = *(const short4v*)o1;
}

// ---------------------------------------------------------------------------
// Generic bf16 MFMA GEMM, XCD-aware swizzle. OUTMODE: 0 fp32, 1 bf16*oscale.
// RESMODE: 0/1 (+fp32 res1) /2 (+res1 + s2*bf16 res2).
// ---------------------------------------------------------------------------
template<int BN, int OP, int RESMODE, int OUTMODE>
__global__ __launch_bounds__(256) void bgemm_kernel(
    const bf16* __restrict__ A,
    const bf16* __restrict__ Bt,
    const float* __restrict__ bias,
    const float* __restrict__ res1,
    const bf16* __restrict__ res2,
    float s2, float oscale,
    void* __restrict__ Cout,
    int N, int Kd, int nxb)
{
    constexpr int NT = BN / 32;
    __shared__ alignas(16) bf16 As[128][64];
    __shared__ alignas(16) bf16 Bs[BN][64];
    const int tid  = threadIdx.x;
    const int w    = tid >> 6;
    const int lane = tid & 63;
    const int quad = lane >> 4;
    const int l16  = lane & 15;
    const int wm   = w >> 1, wn = w & 1;

    const int flat = blockIdx.x;
    const int c8   = flat & 7;
    const int j    = flat >> 3;
    const int jy   = j / nxb;
    const int m0   = (c8 * 8 + jy) * 128;
    const int n0   = (j - jy * nxb) * BN;

    const int srow = lane >> 3;
    const int scol = ((lane & 7) ^ srow) * 8;

    const bf16* Ap = A  + (size_t)(m0 + w * 32 + srow) * Kd + scol;
    const bf16* Bp = Bt + (size_t)(n0 + w * (BN / 4) + srow) * Kd + scol;

    f32x4 acc[4][NT] = {};

    for (int k0 = 0; k0 < Kd; k0 += 64) {
        #pragma unroll
        for (int i = 0; i < 4; ++i)
            async_copy16(Ap + (size_t)(i * 8) * Kd + k0, &As[w * 32 + i * 8][0]);
        #pragma unroll
        for (int i = 0; i < BN / 32; ++i)
            async_copy16(Bp + (size_t)(i * 8) * Kd + k0, &Bs[w * (BN / 4) + i * 8][0]);
        __syncthreads();
        #pragma unroll
        for (int ks = 0; ks < 2; ++ks) {
            short8 af[4], bfr[NT];
            #pragma unroll
            for (int mt = 0; mt < 4; ++mt) {
                const int row = wm * 64 + mt * 16 + l16;
                const int c   = ((ks * 4 + quad) ^ (row & 7)) * 16;
                af[mt] = *(const short8*)((const char*)&As[row][0] + c);
            }
            #pragma unroll
            for (int nt = 0; nt < NT; ++nt) {
                const int col = wn * (BN / 2) + nt * 16 + l16;
                const int c   = ((ks * 4 + quad) ^ (col & 7)) * 16;
                bfr[nt] = *(const short8*)((const char*)&Bs[col][0] + c);
            }
            #pragma unroll
            for (int mt = 0; mt < 4; ++mt)
                #pragma unroll
                for (int nt = 0; nt < NT; ++nt)
                    acc[mt][nt] = __builtin_amdgcn_mfma_f32_16x16x32_bf16(
                        af[mt], bfr[nt], acc[mt][nt], 0, 0, 0);
        }
        __syncthreads();
    }

    const int crow0 = m0 + wm * 64 + quad * 4;
    const int ccol0 = n0 + wn * (BN / 2) + l16;
    #pragma unroll
    for (int nt = 0; nt < NT; ++nt) {
        const int col = ccol0 + nt * 16;
        const float bv = bias[col];
        #pragma unroll
        for (int mt = 0; mt < 4; ++mt) {
            #pragma unroll
            for (int r = 0; r < 4; ++r) {
                const int row = crow0 + mt * 16 + r;
                const size_t off = (size_t)row * N + col;
                float o = acc[mt][nt][r] + bv;
                if (OP == 1)      o = fmaxf(o, 0.f);
                else if (OP == 2) o = gelu_exact(o);
                if (RESMODE >= 1) o += res1[off];
                if (RESMODE == 2) o += s2 * __bfloat162float(res2[off]);
                if (OUTMODE == 0) ((float*)Cout)[off] = o;
                else              ((bf16*)Cout)[off]  = __float2bfloat16(o * oscale);
            }
        }
    }
}

// ---------------------------------------------------------------------------
// Fused FF1 + QKV super-GEMM (both K=512, M=8192):
//   blocks 0..1023:    h1 = relu(lnb @ Wff1t + bff1) -> bigb        (N=2048)
//   blocks 1024..1791: qkv = lnab @ Wqkvt + bqkv; Q/K -> qkvb,
//                      V -> Vtb transposed (packed 8B stores)        (N=1536)
// ---------------------------------------------------------------------------
__global__ __launch_bounds__(256) void ffqkv_kernel(
    const bf16* __restrict__ lnb, const bf16* __restrict__ lnab,
    const bf16* __restrict__ Wff1t, const bf16* __restrict__ Wqkvt,
    const float* __restrict__ bff1, const float* __restrict__ bqkv,
    bf16* __restrict__ bigb, bf16* __restrict__ qkvb, bf16* __restrict__ Vtb)
{
    __shared__ alignas(16) bf16 As[128][64];
    __shared__ alignas(16) bf16 Bs[128][64];
    const int tid  = threadIdx.x;
    const int w    = tid >> 6;
    const int lane = tid & 63;
    const int quad = lane >> 4;
    const int l16  = lane & 15;
    const int wm   = w >> 1, wn = w & 1;

    const bool jobq = blockIdx.x >= 1024;
    const int  flat = jobq ? (int)blockIdx.x - 1024 : (int)blockIdx.x;
    const int  nxb  = jobq ? 12 : 16;
    const int  N    = jobq ? QKVN : FFD;
    const bf16* A   = jobq ? lnab : lnb;
    const bf16* Bt  = jobq ? Wqkvt : Wff1t;
    const float* bias = jobq ? bqkv : bff1;

    const int c8 = flat & 7;
    const int j  = flat >> 3;
    const int jy = j / nxb;
    const int m0 = (c8 * 8 + jy) * 128;
    const int n0 = (j - jy * nxb) * 128;

    const int srow = lane >> 3;
    const int scol = ((lane & 7) ^ srow) * 8;

    const bf16* Ap = A  + (size_t)(m0 + w * 32 + srow) * DD + scol;
    const bf16* Bp = Bt + (size_t)(n0 + w * 32 + srow) * DD + scol;

    f32x4 acc[4][4] = {};

    for (int k0 = 0; k0 < DD; k0 += 64) {
        #pragma unroll
        for (int i = 0; i < 4; ++i) {
            async_copy16(Ap + (size_t)(i * 8) * DD + k0, &As[w * 32 + i * 8][0]);
            async_copy16(Bp + (size_t)(i * 8) * DD + k0, &Bs[w * 32 + i * 8][0]);
        }
        __syncthreads();
        #pragma unroll
        for (int ks = 0; ks < 2; ++ks) {
            short8 af[4], bfr[4];
            #pragma unroll
            for (int mt = 0; mt < 4; ++mt) {
                const int row = wm * 64 + mt * 16 + l16;
                const int c   = ((ks * 4 + quad) ^ (row & 7)) * 16;
                af[mt] = *(const short8*)((const char*)&As[row][0] + c);
            }
            #pragma unroll
            for (int nt = 0; nt < 4; ++nt) {
                const int col = wn * 64 + nt * 16 + l16;
                const int c   = ((ks * 4 + quad) ^ (col & 7)) * 16;
                bfr[nt] = *(const short8*)((const char*)&Bs[col][0] + c);
            }
            #pragma unroll
            for (int mt = 0; mt < 4; ++mt)
                #pragma unroll
                for (int nt = 0; nt < 4; ++nt)
                    acc[mt][nt] = __builtin_amdgcn_mfma_f32_16x16x32_bf16(
                        af[mt], bfr[nt], acc[mt][nt], 0, 0, 0);
        }
        __syncthreads();
    }

    const int crow0 = m0 + wm * 64 + quad * 4;
    const int ccol0 = n0 + wn * 64 + l16;
    #pragma unroll
    for (int nt = 0; nt < 4; ++nt) {
        const int col = ccol0 + nt * 16;
        const float bv = bias[col];
        #pragma unroll
        for (int mt = 0; mt < 4; ++mt) {
            if (jobq) {
                alignas(8) bf16 o4[4];
                #pragma unroll
                for (int r = 0; r < 4; ++r)
                    o4[r] = __float2bfloat16(acc[mt][nt][r] + bv);
                if (col < 1024) {
                    #pragma unroll
                    for (int r = 0; r < 4; ++r)
                        qkvb[(size_t)(crow0 + mt * 16 + r) * QKVN + col] = o4[r];
                } else {
                    const int dg   = col - 1024;
                    const int rowt = crow0 + mt * 16;
                    const int bb   = rowt >> 10, t0 = rowt & 1023;
                    const int bh2  = bb * 8 + (dg >> 6), d = dg & 63;
                    *(short4v*)(Vtb + ((size_t)bh2 * 64 + d) * TT + t0) =
                        *(const short4v*)o4;
                }
            } else {
                #pragma unroll
                for (int r = 0; r < 4; ++r) {
                    const float o = fmaxf(acc[mt][nt][r] + bv, 0.f);
                    bigb[(size_t)(crow0 + mt * 16 + r) * FFD + col] =
                        __float2bfloat16(o);
                }
            }
        }
    }
}

// ---------------------------------------------------------------------------
// Fused FF2 + flash-attention super-kernel (both consume ffqkv outputs only):
//   blocks 0..511:    fattn v4 (128 q/block, LDS-shared K/V, permuted-K S^T,
//                     static softmax)
//   blocks 512..1023: xff = bigb @ Wff2t + bff2 -> bf16 xffb (BN=64, K=2048)
// 32 KB LDS union. Long fattn blocks dispatch first (tail leveling).
// ---------------------------------------------------------------------------
__global__ __launch_bounds__(256) void ff2attn_kernel(
    const bf16* __restrict__ QKV, const bf16* __restrict__ Vt,
    bf16* __restrict__ ctx,
    const bf16* __restrict__ bigb, const bf16* __restrict__ Wff2t,
    const float* __restrict__ bff2, bf16* __restrict__ xffb)
{
    __shared__ alignas(16) bf16 smem[16384];   // 32 KB
    const int tid  = threadIdx.x;
    const int w    = tid >> 6;
    const int lane = tid & 63;
    const int quad = lane >> 4;
    const int l16  = lane & 15;

    if (blockIdx.x < 512) {
        // ---------------- flash attention v4 ----------------
        typedef bf16 (*tile_t)[64][64];
        tile_t Ks = (tile_t)smem;                    // Ks[2][64][64]
        tile_t Vs = (tile_t)(smem + 2 * 64 * 64);    // Vs[2][64][64]
        const int bh = blockIdx.x & 63;
        const int bi = 7 - ((int)blockIdx.x >> 6);   // long blocks first
        const int b = bh >> 3, h = bh & 7;

        const bf16* Qg = QKV + (size_t)(b * TT) * QKVN + h * 64;
        const bf16* Kg = QKV + (size_t)(b * TT) * QKVN + 512 + h * 64;
        const bf16* Vg = Vt  + (size_t)bh * 64 * TT;

        const int qL = bi * 128 + w * 16;
        const int qH = qL + 64;
        short8 qfL0 = *(const short8*)(Qg + (size_t)(qL + l16) * QKVN + quad * 8);
        short8 qfL1 = *(const short8*)(Qg + (size_t)(qL + l16) * QKVN + 32 + quad * 8);
        short8 qfH0 = *(const short8*)(Qg + (size_t)(qH + l16) * QKVN + quad * 8);
        short8 qfH1 = *(const short8*)(Qg + (size_t)(qH + l16) * QKVN + 32 + quad * 8);

        const int sgrow  = lane >> 3;
        const int sgchnk = lane & 7;

        f32x4 caccL[4] = {}, caccH[4] = {};
        float lL = 0.f, lH = 0.f;
        const int prow_base = ((l16 >> 2) << 3) + (l16 & 3);
        const int smax = 2 * bi + 1;

        #pragma unroll
        for (int i = 0; i < 2; ++i) {
            const int rowbase = w * 8 + i * 32;
            const int row = rowbase + sgrow;
            const int fR = (row & 3) | (((row >> 3) & 1) << 2);
            const int sc = sgchnk ^ fR;
            async_copy16(Kg + (size_t)row * QKVN + sc * 8, &Ks[0][rowbase][0]);
            async_copy16(Vg + (size_t)row * TT + sc * 8,   &Vs[0][rowbase][0]);
        }

        int buf = 0;
        for (int s = 0; s <= smax; ++s) {
            __syncthreads();
            if (s < smax) {
                const int kn = (s + 1) * 64;
                #pragma unroll
                for (int i = 0; i < 2; ++i) {
                    const int rowbase = w * 8 + i * 32;
                    const int row = rowbase + sgrow;
                    const int fR = (row & 3) | (((row >> 3) & 1) << 2);
                    const int sc = sgchnk ^ fR;
                    async_copy16(Kg + (size_t)(kn + row) * QKVN + sc * 8,
                                 &Ks[buf ^ 1][rowbase][0]);
                    async_copy16(Vg + (size_t)row * TT + kn + sc * 8,
                                 &Vs[buf ^ 1][rowbase][0]);
                }
            }
            const int k0 = s * 64;
            const bool doL = (s < smax);

            f32x4 sTL[4], sTH[4];
            #pragma unroll
            for (int s4 = 0; s4 < 4; ++s4) {
                const int prow = prow_base + (s4 >> 1) * 32 + (s4 & 1) * 4;
                const int fR = (prow & 3) | (((prow >> 3) & 1) << 2);
                short8 ka = *(const short8*)&Ks[buf][prow][(quad ^ fR) * 8];
                short8 kb = *(const short8*)&Ks[buf][prow][((4 + quad) ^ fR) * 8];
                f32x4 zH = {0.f, 0.f, 0.f, 0.f};
                zH = __builtin_amdgcn_mfma_f32_16x16x32_bf16(ka, qfH0, zH, 0, 0, 0);
                sTH[s4] = __builtin_amdgcn_mfma_f32_16x16x32_bf16(kb, qfH1, zH, 0, 0, 0);
                if (doL) {
                    f32x4 zL = {0.f, 0.f, 0.f, 0.f};
                    zL = __builtin_amdgcn_mfma_f32_16x16x32_bf16(ka, qfL0, zL, 0, 0, 0);
                    sTL[s4] = __builtin_amdgcn_mfma_f32_16x16x32_bf16(kb, qfL1, zL, 0, 0, 0);
                }
            }

            alignas(16) bf16 pbH[16], pbL[16];
            if (s == smax) {
                const int qg = qH + l16;
                #pragma unroll
                for (int s4 = 0; s4 < 4; ++s4)
                    #pragma unroll
                    for (int r = 0; r < 4; ++r) {
                        const int key = k0 + (s4 >> 1) * 32 + quad * 8 + (s4 & 1) * 4 + r;
                        const float p = (key <= qg) ? __expf(sTH[s4][r]) : 0.f;
                        lH += p;
                        pbH[s4 * 4 + r] = __float2bfloat16(p);
                    }
            } else {
                #pragma unroll
                for (int s4 = 0; s4 < 4; ++s4)
                    #pragma unroll
                    for (int r = 0; r < 4; ++r) {
                        const float p = __expf(sTH[s4][r]);
                        lH += p;
                        pbH[s4 * 4 + r] = __float2bfloat16(p);
                    }
            }
            if (doL) {
                if (s == smax - 1) {
                    const int qg = qL + l16;
                    #pragma unroll
                    for (int s4 = 0; s4 < 4; ++s4)
                        #pragma unroll
                        for (int r = 0; r < 4; ++r) {
                            const int key = k0 + (s4 >> 1) * 32 + quad * 8 + (s4 & 1) * 4 + r;
                            const float p = (key <= qg) ? __expf(sTL[s4][r]) : 0.f;
                            lL += p;
                            pbL[s4 * 4 + r] = __float2bfloat16(p);
                        }
                } else {
                    #pragma unroll
                    for (int s4 = 0; s4 < 4; ++s4)
                        #pragma unroll
                        for (int r = 0; r < 4; ++r) {
                            const float p = __expf(sTL[s4][r]);
                            lL += p;
                            pbL[s4 * 4 + r] = __float2bfloat16(p);
                        }
                }
            }
            const short8 pfH0 = *(const short8*)&pbH[0];
            const short8 pfH1 = *(const short8*)&pbH[8];
            const short8 pfL0 = *(const short8*)&pbL[0];
            const short8 pfL1 = *(const short8*)&pbL[8];

            #pragma unroll
            for (int g = 0; g < 4; ++g) {
                const int vrow = g * 16 + l16;
                const int fR = (vrow & 3) | (((vrow >> 3) & 1) << 2);
                short8 va = *(const short8*)&Vs[buf][vrow][(quad ^ fR) * 8];
                short8 vb = *(const short8*)&Vs[buf][vrow][((4 + quad) ^ fR) * 8];
                caccH[g] = __builtin_amdgcn_mfma_f32_16x16x32_bf16(va, pfH0, caccH[g], 0, 0, 0);
                caccH[g] = __builtin_amdgcn_mfma_f32_16x16x32_bf16(vb, pfH1, caccH[g], 0, 0, 0);
                if (doL) {
                    caccL[g] = __builtin_amdgcn_mfma_f32_16x16x32_bf16(va, pfL0, caccL[g], 0, 0, 0);
                    caccL[g] = __builtin_amdgcn_mfma_f32_16x16x32_bf16(vb, pfL1, caccL[g], 0, 0, 0);
                }
            }
            buf ^= 1;
        }

        lL += __shfl_xor(lL, 16, 64);
        lL += __shfl_xor(lL, 32, 64);
        lH += __shfl_xor(lH, 16, 64);
        lH += __shfl_xor(lH, 32, 64);
        const float invL = 1.0f / lL;
        const float invH = 1.0f / lH;

        bf16* CbL = ctx + (size_t)(b * TT + qL + l16) * DD + h * 64;
        bf16* CbH = ctx + (size_t)(b * TT + qH + l16) * DD + h * 64;
        #pragma unroll
        for (int g = 0; g < 4; ++g) {
            alignas(8) bf16 oL[4], oH[4];
            #pragma unroll
            for (int r = 0; r < 4; ++r) {
                oL[r] = __float2bfloat16(caccL[g][r] * invL);
                oH[r] = __float2bfloat16(caccH[g][r] * invH);
            }
            *(short4v*)(CbL + g * 16 + quad * 4) = *(const short4v*)oL;
            *(short4v*)(CbH + g * 16 + quad * 4) = *(const short4v*)oH;
        }
    } else {
        // ---------------- FF2: xff = bigb @ Wff2t + bff2 ----------------
        typedef bf16 (*row_t)[64];
        row_t As = (row_t)smem;               // 128 rows
        row_t Bs = (row_t)(smem + 128 * 64);  // 64 rows
        const int wm = w >> 1, wn = w & 1;

        const int flat = (int)blockIdx.x - 512;
        const int c8 = flat & 7;
        const int j  = flat >> 3;
        const int jy = j >> 3;          // nxb = 8
        const int m0 = (c8 * 8 + jy) * 128;
        const int n0 = (j & 7) * 64;

        const int srow = lane >> 3;
        const int scol = ((lane & 7) ^ srow) * 8;

        const bf16* Ap = bigb  + (size_t)(m0 + w * 32 + srow) * FFD + scol;
        const bf16* Bp = Wff2t + (size_t)(n0 + w * 16 + srow) * FFD + scol;

        f32x4 acc[4][2] = {};

        for (int k0 = 0; k0 < FFD; k0 += 64) {
            #pragma unroll
            for (int i = 0; i < 4; ++i)
                async_copy16(Ap + (size_t)(i * 8) * FFD + k0, &As[w * 32 + i * 8][0]);
            #pragma unroll
            for (int i = 0; i < 2; ++i)
                async_copy16(Bp + (size_t)(i * 8) * FFD + k0, &Bs[w * 16 + i * 8][0]);
            __syncthreads();
            #pragma unroll
            for (int ks = 0; ks < 2; ++ks) {
                short8 af[4], bfr[2];
                #pragma unroll
                for (int mt = 0; mt < 4; ++mt) {
                    const int row = wm * 64 + mt * 16 + l16;
                    const int c   = ((ks * 4 + quad) ^ (row & 7)) * 16;
                    af[mt] = *(const short8*)((const char*)&As[row][0] + c);
                }
                #pragma unroll
                for (int nt = 0; nt < 2; ++nt) {
                    const int col = wn * 32 + nt * 16 + l16;
                    const int c   = ((ks * 4 + quad) ^ (col & 7)) * 16;
                    bfr[nt] = *(const short8*)((const char*)&Bs[col][0] + c);
                }
                #pragma unroll
                for (int mt = 0; mt < 4; ++mt)
                    #pragma unroll
                    for (int nt = 0; nt < 2; ++nt)
                        acc[mt][nt] = __builtin_amdgcn_mfma_f32_16x16x32_bf16(
                            af[mt], bfr[nt], acc[mt][nt], 0, 0, 0);
            }
            __syncthreads();
        }

        const int crow0 = m0 + wm * 64 + quad * 4;
        const int ccol0 = n0 + wn * 32 + l16;
        #pragma unroll
        for (int nt = 0; nt < 2; ++nt) {
            const int col = ccol0 + nt * 16;
            const float bv = bff2[col];
            #pragma unroll
            for (int mt = 0; mt < 4; ++mt)
                #pragma unroll
                for (int r = 0; r < 4; ++r) {
                    const int row = crow0 + mt * 16 + r;
                    xffb[(size_t)row * DD + col] =
                        __float2bfloat16(acc[mt][nt][r] + bv);
                }
        }
    }
}

// ---------------------------------------------------------------------------
// Depthwise causal conv (k=15) + BN + swish, register sliding window v2:
// thread = 2 channels x 16 consecutive t. 30 u32 loads per 16 output pairs
// (vs 22 per 8 in v1 — 1.47x fewer load instructions). BN folded to s*a + c.
// ---------------------------------------------------------------------------
__global__ __launch_bounds__(256) void dwconv_kernel(const bf16* __restrict__ c1,
                                                     const float* __restrict__ dwk,
                                                     const float* __restrict__ dwb,
                                                     const float* __restrict__ bn_g,
                                                     const float* __restrict__ bn_b,
                                                     const float* __restrict__ bn_m,
                                                     const float* __restrict__ bn_v,
                                                     bf16* __restrict__ out) {
    const int C2 = 2 * DD;   // 1024
    const int lin = blockIdx.x * 256 + threadIdx.x;   // 512 chp * 512 chunks
    const int chp = lin & 511;
    const int ch  = chp << 1;
    const int tch = lin >> 9;          // wave-uniform
    const int row0 = tch << 4;         // global row (b*1024 + t), 16 rows
    const int t0   = row0 & (TT - 1);

    float w0[KW], w1[KW];
    #pragma unroll
    for (int i = 0; i < KW; ++i) {
        w0[i] = dwk[i * C2 + ch];
        w1[i] = dwk[i * C2 + ch + 1];
    }
    const float a0 = rsqrtf(bn_v[ch] + 1e-3f) * bn_g[ch];
    const float a1 = rsqrtf(bn_v[ch + 1] + 1e-3f) * bn_g[ch + 1];
    const float c0 = (dwb[ch] - bn_m[ch]) * a0 + bn_b[ch];
    const float c1v = (dwb[ch + 1] - bn_m[ch + 1]) * a1 + bn_b[ch + 1];

    float x0[30], x1[30];
    if (t0 >= KW - 1) {
        #pragma unroll
        for (int i = 0; i < 30; ++i) {
            unsigned u = *(const unsigned*)(c1 + (size_t)(row0 - (KW - 1) + i) * C2 + ch);
            x0[i] = bf2f(u & 0xffff);
            x1[i] = bf2f(u >> 16);
        }
    } else {   // t0 == 0: guard the causal left edge (zero pad)
        #pragma unroll
        for (int i = 0; i < 30; ++i) {
            unsigned u = 0;
            if (t0 - (KW - 1) + i >= 0)
                u = *(const unsigned*)(c1 + (size_t)(row0 - (KW - 1) + i) * C2 + ch);
            x0[i] = bf2f(u & 0xffff);
            x1[i] = bf2f(u >> 16);
        }
    }

    #pragma unroll
    for (int j = 0; j < 16; ++j) {
        float s0 = 0.f, s1 = 0.f;
        #pragma unroll
        for (int i = 0; i < KW; ++i) {
            s0 += x0[j + i] * w0[i];
            s1 += x1[j + i] * w1[i];
        }
        s0 = s0 * a0 + c0;
        s1 = s1 * a1 + c1v;
        s0 = s0 / (1.f + __expf(-s0));
        s1 = s1 / (1.f + __expf(-s1));
        alignas(4) bf16 ob[2] = {__float2bfloat16(s0), __float2bfloat16(s1)};
        *(unsigned*)(out + (size_t)(row0 + j) * C2 + ch) = *(const unsigned*)ob;
    }
}

// ---------------------------------------------------------------------------
extern "C" void kernel_launch(void* const* d_in, const int* in_sizes, int n_in,
                              void* d_out, int out_size, void* d_ws, size_t ws_size,
                              hipStream_t stream) {
    const float* x    = (const float*)d_in[0];
    const float* g1   = (const float*)d_in[1];
    const float* b1   = (const float*)d_in[2];
    const float* Wff1 = (const float*)d_in[3];
    const float* bff1 = (const float*)d_in[4];
    const float* Wff2 = (const float*)d_in[5];
    const float* bff2 = (const float*)d_in[6];
    const float* ga   = (const float*)d_in[7];
    const float* ba   = (const float*)d_in[8];
    const float* Wq   = (const float*)d_in[9];
    const float* bq   = (const float*)d_in[10];
    const float* Wk   = (const float*)d_in[11];
    const float* bk   = (const float*)d_in[12];
    const float* Wv   = (const float*)d_in[13];
    const float* bv   = (const float*)d_in[14];
    const float* Wo   = (const float*)d_in[15];
    const float* bo   = (const float*)d_in[16];
    const float* gc   = (const float*)d_in[17];
    const float* bc   = (const float*)d_in[18];
    const float* Wcp  = (const float*)d_in[19];
    const float* bcp  = (const float*)d_in[20];
    const float* dwk  = (const float*)d_in[21];
    const float* dwb  = (const float*)d_in[22];
    const float* bn_g = (const float*)d_in[23];
    const float* bn_b = (const float*)d_in[24];
    const float* bn_m = (const float*)d_in[25];
    const float* bn_v = (const float*)d_in[26];
    const float* Wco  = (const float*)d_in[27];
    const float* bco  = (const float*)d_in[28];
    const float* g2   = (const float*)d_in[29];
    const float* b2   = (const float*)d_in[30];
    const float* Wf1  = (const float*)d_in[31];
    const float* bf1  = (const float*)d_in[32];
    const float* Wf2  = (const float*)d_in[33];
    const float* bf2  = (const float*)d_in[34];

    float* out = (float*)d_out;

    // ---- workspace layout ----
    char* p = (char*)d_ws;
    bf16* lnb   = (bf16*)p;  p += (size_t)MR * DD * 2;
    bf16* lnab  = (bf16*)p;  p += (size_t)MR * DD * 2;
    bf16* qkvb  = (bf16*)p;  p += (size_t)MR * QKVN * 2;
    bf16* Vtb   = (bf16*)p;  p += (size_t)MR * DD * 2;
    bf16* ctxb  = (bf16*)p;  p += (size_t)MR * DD * 2;
    bf16* xffb  = (bf16*)p;  p += (size_t)MR * DD * 2;
    bf16* bigb  = (bf16*)p;  p += (size_t)MR * FFD * 2;
    bf16* c2b   = (bf16*)p;  p += (size_t)MR * 1024 * 2;
    bf16* Wff1t = (bf16*)p;  p += (size_t)FFD * DD * 2;
    bf16* Wff2t = (bf16*)p;  p += (size_t)DD * FFD * 2;
    bf16* Wqkvt = (bf16*)p;  p += (size_t)QKVN * DD * 2;
    bf16* Wot   = (bf16*)p;  p += (size_t)DD * DD * 2;
    bf16* Wcpt  = (bf16*)p;  p += (size_t)1024 * DD * 2;
    bf16* Wcot  = (bf16*)p;  p += (size_t)DD * 1024 * 2;
    bf16* Wf1t  = (bf16*)p;  p += (size_t)FFD * DD * 2;
    bf16* Wf2t  = (bf16*)p;  p += (size_t)DD * FFD * 2;
    float* bqkv = (float*)p; p += QKVN * 4;

    dim3 blk(256);

    PrepPack P;
    auto set = [&](int i, const float* s, bf16* d, int K, int N, float sc, int off) {
        P.src[i] = s; P.dst[i] = d; P.K[i] = K; P.scale[i] = sc; P.off[i] = off;
        int nt = N / 64, lg = 0; while ((1 << lg) < nt) ++lg; P.lgNT[i] = lg;
    };
    set(0, Wff1, Wff1t, DD,  FFD, 1.f,    0);
    set(1, Wff2, Wff2t, FFD, DD,  1.f,    256);
    set(2, Wq,   Wqkvt,                DD, DD, 0.125f, 512);
    set(3, Wk,   Wqkvt + (size_t)512 * DD,  DD, DD, 1.f, 576);
    set(4, Wv,   Wqkvt + (size_t)1024 * DD, DD, DD, 1.f, 640);
    set(5, Wo,   Wot,   DD,  DD,  1.f,    704);
    set(6, Wcp,  Wcpt,  DD,  1024, 1.f,   768);
    set(7, Wco,  Wcot,  1024, DD, 1.f,    896);
    set(8, Wf1,  Wf1t,  DD,  FFD, 1.f,    1024);
    set(9, Wf2,  Wf2t,  FFD, DD,  1.f,    1280);
    P.bq = bq; P.bk = bk; P.bv = bv; P.bdst = bqkv;
    P.x = x; P.g1 = g1; P.b1 = b1; P.ga = ga; P.ba = ba;
    P.o1 = lnb; P.o2 = lnab;

    // 1. prep: weight transposes + bias concat + dual LN (all independent)
    prep_kernel<<<dim3(1537 + MR / 4), blk, 0, stream>>>(P);
    // 2. fused FF1 + QKV (both K=512; QKV emits Q/K + V^T)
    ffqkv_kernel<<<dim3(1024 + 768), blk, 0, stream>>>(
        lnb, lnab, Wff1t, Wqkvt, bff1, bqkv, bigb, qkvb, Vtb);
    // 3. fused flash-attention + FF2 (independent consumers of step 2)
    ff2attn_kernel<<<dim3(1024), blk, 0, stream>>>(
        qkvb, Vtb, ctxb, bigb, Wff2t, bff2, xffb);
    // 4. x1 = x + 0.5*xff + (ctx @ Wo + bo) -> fp32 d_out   (BN=64, nxb=8)
    bgemm_kernel<64, 0, 2, 0><<<dim3(8 * 64), blk, 0, stream>>>(
        ctxb, Wot, bo, x, xffb, 0.5f, 1.f, out, DD, DD, 8);
    // 5. lnc = LN(x1) -> bf16
    ln_kernel<<<dim3(MR / 4), blk, 0, stream>>>(out, gc, bc, lnb);
    // 6. c1 = gelu(lnc @ Wcp + bcp) -> bf16   (nxb = 8)
    bgemm_kernel<128, 2, 0, 1><<<dim3(8 * 64), blk, 0, stream>>>(
        lnb, Wcpt, bcp, nullptr, nullptr, 0.f, 1.f, bigb, 1024, DD, 8);
    // 7. c2 = swish(BN(dwconv(c1))) -> bf16   (16 t per thread)
    dwconv_kernel<<<dim3(MR * 512 / 16 / 256), blk, 0, stream>>>(
        bigb, dwk, dwb, bn_g, bn_b, bn_m, bn_v, c2b);
    // 8. x2 = x1 + (c2 @ Wco + bco) -> fp32 d_out (in-place, BN=64, nxb=8)
    bgemm_kernel<64, 0, 1, 0><<<dim3(8 * 64), blk, 0, stream>>>(
        c2b, Wcot, bco, out, nullptr, 0.f, 1.f, out, DD, 1024, 8);
    // 9. ln2 = LN(x2) -> bf16
    ln_kernel<<<dim3(MR / 4), blk, 0, stream>>>(out, g2, b2, lnb);
    // 10. h2 = relu(ln2 @ Wf1 + bf1) -> bf16   (nxb = 16)
    bgemm_kernel<128, 1, 0, 1><<<dim3(16 * 64), blk, 0, stream>>>(
        lnb, Wf1t, bf1, nullptr, nullptr, 0.f, 1.f, bigb, FFD, DD, 16);
    // 11. out = x2 + (h2 @ Wf2 + bf2) -> fp32 d_out   (BN=64, nxb=8)
    bgemm_kernel<64, 0, 1, 0><<<dim3(8 * 64), blk, 0, stream>>>(
        bigb, Wf2t, bf2, out, nullptr, 0.f, 1.f, out, DD, FFD, 8);
}